// Round 4
// baseline (214.748 us; speedup 1.0000x reference)
//
#include <hip/hip_runtime.h>

#define NB 2000000
static constexpr float EPSF = 1e-4f;

// Stage-through-LDS design:
//  - Phase 1: each block copies its 256 rows of all 4 input planes into LDS
//    with pure coalesced float4 copies (LDS layout == memory layout, no
//    index transform). This is the copy-kernel access pattern (~6.3 TB/s).
//  - Phase 2: thread t reads row t's 15 floats from LDS and computes.
// Rationale: direct per-row loads (round 2/3) trigger a compiler spill
// pathology (VGPR=16, 244 MB scratch traffic); 4-row blocking (round 1)
// compiles clean but has 96B-lane-stride loads that cap the TA pipe at
// ~2.9 TB/s. LDS staging gives coalesced streams AND a small register
// footprint.
__global__ __launch_bounds__(256) void gcnl_kernel(
    const float* __restrict__ pred_r,
    const float* __restrict__ pred_params,
    const float* __restrict__ pred_corr,
    const float* __restrict__ y_true,
    float* __restrict__ out)
{
    __shared__ __align__(16) float s_pr[256 * 2];  // 2 f/row
    __shared__ __align__(16) float s_pp[256 * 6];  // 6 f/row
    __shared__ __align__(16) float s_pc[256 * 3];  // 3 f/row
    __shared__ __align__(16) float s_yt[256 * 4];  // 4 f/row

    const int t = threadIdx.x;
    const int base_row = blockIdx.x << 8;
    const int rows = min(256, NB - base_row);  // last block: 128

    // ---- phase 1: block-contiguous float4 copies, global -> LDS ----
    {
        const float4* p = (const float4*)pred_r + (base_row >> 1);
        const int n4 = (rows * 2) >> 2;
        for (int idx = t; idx < n4; idx += 256) ((float4*)s_pr)[idx] = p[idx];
    }
    {
        const float4* p = (const float4*)pred_params + ((base_row * 6) >> 2);
        const int n4 = (rows * 6) >> 2;
        for (int idx = t; idx < n4; idx += 256) ((float4*)s_pp)[idx] = p[idx];
    }
    {
        const float4* p = (const float4*)pred_corr + ((base_row * 3) >> 2);
        const int n4 = (rows * 3) >> 2;
        for (int idx = t; idx < n4; idx += 256) ((float4*)s_pc)[idx] = p[idx];
    }
    {
        const float4* p = (const float4*)y_true + base_row;
        const int n4 = rows;
        for (int idx = t; idx < n4; idx += 256) ((float4*)s_yt)[idx] = p[idx];
    }
    __syncthreads();

    // ---- phase 2: per-row compute from LDS ----
    float acc = 0.0f;
    if (t < rows) {
        const float r0 = s_pr[t * 2 + 0], r1 = s_pr[t * 2 + 1];
        const float pp0 = s_pp[t * 6 + 0], pp1 = s_pp[t * 6 + 1];
        const float pp2 = s_pp[t * 6 + 2], pp3 = s_pp[t * 6 + 3];
        const float pp4 = s_pp[t * 6 + 4], pp5 = s_pp[t * 6 + 5];
        const float r12 = s_pc[t * 3 + 0], r13 = s_pc[t * 3 + 1], r23 = s_pc[t * 3 + 2];
        const float revert = s_yt[t * 4 + 0], Rtop = s_yt[t * 4 + 1];
        const float Top = s_yt[t * 4 + 2], Close = s_yt[t * 4 + 3];

        // s = exp(pp) => 1/s = exp(-pp), 0.5*log(s^2) = pp
        const float rtop  = __expf(pp0), is_rtop  = __expf(-pp1);
        const float top   = __expf(pp2), is_top   = __expf(-pp3);
        const float close = __expf(pp4), is_close = __expf(-pp5);

        const float d1 = (rtop  - Rtop ) * is_rtop;
        const float d2 = (top   - Top  ) * is_top;
        const float d3 = (close - Close) * is_close;

        // z = clip((x-u)/s, -3, 3): ndtr/erfinv round-trip collapses (eps-clip outside +-3)
        const float z1 = fminf(fmaxf(-d1, -3.0f), 3.0f);
        const float z2 = fminf(fmaxf(-d2, -3.0f), 3.0f);
        const float z3 = fminf(fmaxf(-d3, -3.0f), 3.0f);

        const float detR = 1.0f + 2.0f*r12*r13*r23 - r12*r12 - r13*r13 - r23*r23;
        const float inv_det = 1.0f / detR;
        const float i00 = (1.0f - r23*r23) * inv_det;
        const float i01 = (r13*r23 - r12) * inv_det;
        const float i02 = (r12*r23 - r13) * inv_det;
        const float i11 = (1.0f - r13*r13) * inv_det;
        const float i12 = (r12*r13 - r23) * inv_det;
        const float i22 = (1.0f - r12*r12) * inv_det;

        const float exp_term = 0.5f*((i00-1.0f)*z1*z1 + (i11-1.0f)*z2*z2 + (i22-1.0f)*z3*z3)
                             + (i01*z1*z2 + i02*z1*z3 + i12*z2*z3);
        const float c_gauss = 0.5f*__logf(fmaxf(detR, EPSF)) + exp_term;
        const float nll = 0.5f*(d1*d1 + d2*d2 + d3*d3) + (pp1 + pp3 + pp5);
        const float copula = revert * (c_gauss + nll);

        // cross-entropy: -logp[sel] = lse - r_sel
        const float m   = fmaxf(r0, r1);
        const float lse = m + __logf(1.0f + __expf(-fabsf(r0 - r1)));
        const float rsel = (revert != 0.0f) ? r1 : r0;

        acc = copula + (lse - rsel);
    }

    // wave (64) shuffle reduce
    #pragma unroll
    for (int off = 32; off > 0; off >>= 1) acc += __shfl_down(acc, off, 64);

    __shared__ float warp_sums[4];
    const int lane = threadIdx.x & 63;
    const int wid  = threadIdx.x >> 6;
    if (lane == 0) warp_sums[wid] = acc;
    __syncthreads();
    if (threadIdx.x == 0) {
        const float s = warp_sums[0] + warp_sums[1] + warp_sums[2] + warp_sums[3];
        atomicAdd(out, s * (1.0f / (float)NB));
    }
}

extern "C" void kernel_launch(void* const* d_in, const int* in_sizes, int n_in,
                              void* d_out, int out_size, void* d_ws, size_t ws_size,
                              hipStream_t stream) {
    const float* pred_r      = (const float*)d_in[0];
    const float* pred_params = (const float*)d_in[1];
    const float* pred_corr   = (const float*)d_in[2];
    const float* y_true      = (const float*)d_in[3];
    float* out = (float*)d_out;

    // output is poisoned (0xAA) before every timed replay -> zero it in-graph
    hipMemsetAsync(out, 0, sizeof(float), stream);

    const int block = 256;
    const int grid = (NB + block - 1) / block;  // 7813
    hipLaunchKernelGGL(gcnl_kernel, dim3(grid), dim3(block), 0, stream,
                       pred_r, pred_params, pred_corr, y_true, out);
}

// Round 5
// 139.294 us; speedup vs baseline: 1.5417x; 1.5417x over previous
//
#include <hip/hip_runtime.h>

#define NB 2000000
static constexpr float EPSF = 1e-4f;

// Round-4 finding: WRITE_SIZE units are KB; 244 KB = 7813 atomics x 32 B
// dirty sectors. All round 2-4 kernels sat on a same-address atomicAdd
// serialization floor: ~13.4 ns/atomic x 7813 = ~105 us. Fix: two-stage
// reduction, zero same-address atomics.
//   Stage 1: 2048 blocks, grid-stride, per-block partial -> d_ws[blockIdx]
//   Stage 2: 1 block sums 2048 partials, writes out = s / NB
__global__ __launch_bounds__(256) void gcnl_main(
    const float* __restrict__ pred_r,
    const float* __restrict__ pred_params,
    const float* __restrict__ pred_corr,
    const float* __restrict__ y_true,
    float* __restrict__ partial)
{
    const int T = gridDim.x * blockDim.x;  // 524288
    float acc = 0.0f;

    for (int i = blockIdx.x * blockDim.x + threadIdx.x; i < NB; i += T) {
        const float2 rr = ((const float2*)pred_r)[i];
        const float2 pa = ((const float2*)pred_params)[3*i + 0];
        const float2 pb = ((const float2*)pred_params)[3*i + 1];
        const float2 pc = ((const float2*)pred_params)[3*i + 2];
        const float  c0 = pred_corr[3*i + 0];
        const float  c1 = pred_corr[3*i + 1];
        const float  c2 = pred_corr[3*i + 2];
        const float4 yt = ((const float4*)y_true)[i];

        const float r0 = rr.x, r1 = rr.y;
        const float pp0 = pa.x, pp1 = pa.y, pp2 = pb.x;
        const float pp3 = pb.y, pp4 = pc.x, pp5 = pc.y;
        const float r12 = c0, r13 = c1, r23 = c2;
        const float revert = yt.x, Rtop = yt.y, Top = yt.z, Close = yt.w;

        // s = exp(pp) => 1/s = exp(-pp), 0.5*log(s^2) = pp
        const float rtop  = __expf(pp0), is_rtop  = __expf(-pp1);
        const float top   = __expf(pp2), is_top   = __expf(-pp3);
        const float close = __expf(pp4), is_close = __expf(-pp5);

        const float d1 = (rtop  - Rtop ) * is_rtop;
        const float d2 = (top   - Top  ) * is_top;
        const float d3 = (close - Close) * is_close;

        // z = clip((x-u)/s, -3, 3): ndtr/erfinv round-trip collapses (eps-clip outside +-3)
        const float z1 = fminf(fmaxf(-d1, -3.0f), 3.0f);
        const float z2 = fminf(fmaxf(-d2, -3.0f), 3.0f);
        const float z3 = fminf(fmaxf(-d3, -3.0f), 3.0f);

        const float detR = 1.0f + 2.0f*r12*r13*r23 - r12*r12 - r13*r13 - r23*r23;
        const float inv_det = 1.0f / detR;
        const float i00 = (1.0f - r23*r23) * inv_det;
        const float i01 = (r13*r23 - r12) * inv_det;
        const float i02 = (r12*r23 - r13) * inv_det;
        const float i11 = (1.0f - r13*r13) * inv_det;
        const float i12 = (r12*r13 - r23) * inv_det;
        const float i22 = (1.0f - r12*r12) * inv_det;

        const float exp_term = 0.5f*((i00-1.0f)*z1*z1 + (i11-1.0f)*z2*z2 + (i22-1.0f)*z3*z3)
                             + (i01*z1*z2 + i02*z1*z3 + i12*z2*z3);
        const float c_gauss = 0.5f*__logf(fmaxf(detR, EPSF)) + exp_term;
        const float nll = 0.5f*(d1*d1 + d2*d2 + d3*d3) + (pp1 + pp3 + pp5);
        const float copula = revert * (c_gauss + nll);

        // cross-entropy: -logp[sel] = lse - r_sel
        const float m   = fmaxf(r0, r1);
        const float lse = m + __logf(1.0f + __expf(-fabsf(r0 - r1)));
        const float rsel = (revert != 0.0f) ? r1 : r0;

        acc += copula + (lse - rsel);
    }

    // wave (64) shuffle reduce
    #pragma unroll
    for (int off = 32; off > 0; off >>= 1) acc += __shfl_down(acc, off, 64);

    __shared__ float warp_sums[4];
    const int lane = threadIdx.x & 63;
    const int wid  = threadIdx.x >> 6;
    if (lane == 0) warp_sums[wid] = acc;
    __syncthreads();
    if (threadIdx.x == 0) {
        partial[blockIdx.x] = warp_sums[0] + warp_sums[1] + warp_sums[2] + warp_sums[3];
    }
}

// Stage 2: one block, 256 threads, sums 2048 partials -> out = s / NB.
__global__ __launch_bounds__(256) void gcnl_reduce(
    const float* __restrict__ partial, float* __restrict__ out)
{
    const int t = threadIdx.x;
    float acc = 0.0f;
    #pragma unroll
    for (int k = 0; k < 8; ++k) acc += partial[t + 256 * k];

    #pragma unroll
    for (int off = 32; off > 0; off >>= 1) acc += __shfl_down(acc, off, 64);

    __shared__ float warp_sums[4];
    const int lane = t & 63;
    const int wid  = t >> 6;
    if (lane == 0) warp_sums[wid] = acc;
    __syncthreads();
    if (t == 0) {
        const float s = warp_sums[0] + warp_sums[1] + warp_sums[2] + warp_sums[3];
        out[0] = s * (1.0f / (float)NB);
    }
}

extern "C" void kernel_launch(void* const* d_in, const int* in_sizes, int n_in,
                              void* d_out, int out_size, void* d_ws, size_t ws_size,
                              hipStream_t stream) {
    const float* pred_r      = (const float*)d_in[0];
    const float* pred_params = (const float*)d_in[1];
    const float* pred_corr   = (const float*)d_in[2];
    const float* y_true      = (const float*)d_in[3];
    float* partial = (float*)d_ws;   // 2048 floats, fully overwritten each call
    float* out = (float*)d_out;

    const int block = 256;
    const int grid = 2048;
    hipLaunchKernelGGL(gcnl_main, dim3(grid), dim3(block), 0, stream,
                       pred_r, pred_params, pred_corr, y_true, partial);
    hipLaunchKernelGGL(gcnl_reduce, dim3(1), dim3(block), 0, stream,
                       partial, out);
}